// Round 12
// baseline (81.775 us; speedup 1.0000x reference)
//
#include <hip/hip_runtime.h>
#include <hip/hip_bf16.h>

// GAT layer, B=4, N=4096, F_in=128, F_out=64.
// out_i = sum_j adj_ij * exp(leaky(s2_i+s1_j)) * Wh_j / sum_j adj_ij*exp(..)
// (softmax normalizer cancels; eps*Z term ~2e-9 relative -> dropped;
//  scores O(8) so bare exp2 safe; s1/s2 pre-scaled by log2 e.)
//
// R12: barrier-free k_main = R5 wave-autonomous structure (P built directly
// in MFMA A-fragment registers, zero LDS/barriers) + R9 fragment-order B
// (contiguous 1KB loads, 16 txns/KB — R5's fatal flaw was its 64-txn/KB
// B gather). 1024 independent waves; full dbuf adj/s1/B, X/Y manual unroll.

typedef __attribute__((ext_vector_type(8))) short bf16x8;
typedef __attribute__((ext_vector_type(4))) float f32x4;
typedef __attribute__((ext_vector_type(4))) unsigned int u32x4;

#define LOG2E 1.4426950408889634f

__device__ __forceinline__ unsigned int pk2(float lo, float hi) {
  float2 f2; f2.x = lo; f2.y = hi;
  union { __hip_bfloat162 b; unsigned int u; } c;
  c.b = __float22bfloat162_rn(f2);
  return c.u;
}
__device__ __forceinline__ bf16x8 u2b(u32x4 v) {
  union { u32x4 u; bf16x8 b; } c; c.u = v; return c.b;
}
__device__ __forceinline__ float vexp2_(float x) {
  float r; asm("v_exp_f32 %0, %1" : "=v"(r) : "v"(x)); return r;
}

// ---------------- K1: Wh = h @ W (f32); wt bf16 in fragment order
//   segment S = (b*128 + k/32)*4 + col/16 (1KB); lane ((k%32)/8)*16+col%16
//   holds 8 shorts (k%8). s1 = Wh a1 * log2e, s2 = Wh a2 * log2e.
__global__ __launch_bounds__(256) void k_wh(
    const float* __restrict__ h, const float* __restrict__ W, const float* __restrict__ a,
    unsigned short* __restrict__ wt, float* __restrict__ s1, float* __restrict__ s2) {
  __shared__ float hs[32][130];
  __shared__ float Ws[128 * 64];
  const int t = threadIdx.x;
  const int b = blockIdx.x >> 7;
  const int row0 = (blockIdx.x & 127) << 5;

  #pragma unroll
  for (int it = 0; it < 8; ++it) {
    const int fidx = it * 256 + t;
    ((float4*)Ws)[fidx] = ((const float4*)W)[fidx];
  }
  #pragma unroll
  for (int it = 0; it < 4; ++it) {
    int flat = it * 256 + t;
    int r = flat >> 5, q = flat & 31;
    const float4 v = *(const float4*)(h + ((size_t)(b * 4096 + row0 + r)) * 128 + 4 * q);
    hs[r][4*q+0] = v.x; hs[r][4*q+1] = v.y; hs[r][4*q+2] = v.z; hs[r][4*q+3] = v.w;
  }
  __syncthreads();

  const int rg = t >> 4, cg = t & 15;
  float acc[2][4] = {};
  for (int k = 0; k < 128; ++k) {
    float4 wv = ((const float4*)Ws)[k * 16 + cg];
    #pragma unroll
    for (int i = 0; i < 2; ++i) {
      float hv = hs[2*rg + i][k];
      acc[i][0] = fmaf(hv, wv.x, acc[i][0]);
      acc[i][1] = fmaf(hv, wv.y, acc[i][1]);
      acc[i][2] = fmaf(hv, wv.z, acc[i][2]);
      acc[i][3] = fmaf(hv, wv.w, acc[i][3]);
    }
  }
  __syncthreads();

  float (*WhF)[68] = (float(*)[68])hs;
  #pragma unroll
  for (int i = 0; i < 2; ++i)
    #pragma unroll
    for (int j = 0; j < 4; ++j)
      WhF[2*rg + i][4*cg + j] = acc[i][j];
  __syncthreads();

  if (t < 32) {
    float x1 = 0.f, x2 = 0.f;
    #pragma unroll 8
    for (int c = 0; c < 64; ++c) {
      float v = WhF[t][c];
      x1 = fmaf(v, a[c], x1);
      x2 = fmaf(v, a[64 + c], x2);
    }
    s1[b * 4096 + row0 + t] = x1 * LOG2E;
    s2[b * 4096 + row0 + t] = x2 * LOG2E;
  }

  const int col = t >> 2, sub = t & 3;
  unsigned int uh[4];
  #pragma unroll
  for (int r = 0; r < 4; ++r)
    uh[r] = pk2(WhF[8*sub + 2*r][col], WhF[8*sub + 2*r + 1][col]);
  const int S = (b * 128 + (row0 >> 5)) * 4 + (col >> 4);
  unsigned short* dst = wt + ((size_t)S << 9) + sub * 128 + (col & 15) * 8;
  *(uint4*)dst = make_uint4(uh[0], uh[1], uh[2], uh[3]);
}

// ---------------- K3: out = P @ Wh, barrier-free. 256 blocks x 256 thr;
// each of the 4 waves owns an independent 16x64 tile (full K=4096).
// Lane l: row lr=l&15, k-chunk 8*(l>>4). K-step 64, X/Y dbuf on all streams.
__global__ __launch_bounds__(256) void k_main(
    const float* __restrict__ adj, const unsigned short* __restrict__ wt,
    const float* __restrict__ s1, const float* __restrict__ s2,
    float* __restrict__ out) {
  const int t = threadIdx.x;
  const int l = t & 63, w = t >> 6;
  const int blk = blockIdx.x;
  const int xcd = blk & 7;                   // default round-robin XCD id
  const int b = xcd >> 1;                    // one batch per XCD pair (wt L2-res)
  const int tile = ((blk >> 3) + ((xcd & 1) << 5)) * 4 + w;   // 0..255 per b
  const int row0 = tile << 4;
  const int lr = l & 15, g = l >> 4;

  const float* adjW = adj + ((size_t)(b * 4096 + row0 + lr)) * 4096 + 8 * g;
  const float* s1W  = s1 + b * 4096 + 8 * g;
  const float s2v   = s2[b * 4096 + row0 + lr];
  const unsigned short* wtW = wt + ((size_t)b << 18) + 8 * l;  // b's segment base

  float sar = 0.f;
  f32x4 acc[4] = {{0.f,0.f,0.f,0.f},{0.f,0.f,0.f,0.f},{0.f,0.f,0.f,0.f},{0.f,0.f,0.f,0.f}};

  f32x4 aX[2][2], aY[2][2], sXv[2][2], sYv[2][2];
  u32x4 bvX[8], bvY[8];

#define LOADADJ(av, sv, ks) do {                                              \
    const int ko = ((ks) & 63) << 6;                                          \
    _Pragma("unroll")                                                         \
    for (int kk = 0; kk < 2; ++kk) {                                          \
      av[kk][0] = *(const f32x4*)(adjW + ko + 32 * kk);                       \
      av[kk][1] = *(const f32x4*)(adjW + ko + 32 * kk + 4);                   \
      sv[kk][0] = *(const f32x4*)(s1W + ko + 32 * kk);                        \
      sv[kk][1] = *(const f32x4*)(s1W + ko + 32 * kk + 4);                    \
    }                                                                         \
  } while (0)

  // fragment-order B: segments ((k32)*4 + cg) within batch base; 1KB each
#define LOADB(bv, ks) do {                                                    \
    const int k32 = ((ks) & 63) << 1;                                         \
    _Pragma("unroll")                                                         \
    for (int kk = 0; kk < 2; ++kk)                                            \
      _Pragma("unroll")                                                       \
      for (int cg = 0; cg < 4; ++cg)                                          \
        bv[kk*4+cg] = *(const u32x4*)(wtW + ((size_t)((k32+kk)*4+cg) << 9));  \
  } while (0)

#define STEPX(av, sv, bv) do {                                                \
    _Pragma("unroll")                                                         \
    for (int kk = 0; kk < 2; ++kk) {                                          \
      float wv[8];                                                            \
      _Pragma("unroll")                                                       \
      for (int j = 0; j < 8; ++j) {                                           \
        float e = s2v + sv[kk][j >> 2][j & 3];                                \
        e = fmaxf(e, 0.2f * e);                                               \
        float p = vexp2_(e);                                                  \
        wv[j] = av[kk][j >> 2][j & 3] * p;                                    \
        sar += wv[j];                                                         \
      }                                                                       \
      union { unsigned int s[4]; u32x4 v; } fu;                               \
      fu.s[0] = pk2(wv[0], wv[1]); fu.s[1] = pk2(wv[2], wv[3]);               \
      fu.s[2] = pk2(wv[4], wv[5]); fu.s[3] = pk2(wv[6], wv[7]);               \
      const bf16x8 frA = u2b(fu.v);                                           \
      _Pragma("unroll")                                                       \
      for (int cg = 0; cg < 4; ++cg)                                          \
        acc[cg] = __builtin_amdgcn_mfma_f32_16x16x32_bf16(                    \
            frA, u2b(bv[kk*4+cg]), acc[cg], 0, 0, 0);                         \
    }                                                                         \
  } while (0)

  LOADADJ(aX, sXv, 0); LOADB(bvX, 0);
  LOADADJ(aY, sYv, 1); LOADB(bvY, 1);

  for (int it = 0; it < 32; ++it) {
    STEPX(aX, sXv, bvX);
    LOADADJ(aX, sXv, 2 * it + 2);   // refill X (wraps harmlessly at end)
    LOADB(bvX, 2 * it + 2);
    STEPX(aY, sYv, bvY);
    LOADADJ(aY, sYv, 2 * it + 3);
    LOADB(bvY, 2 * it + 3);
  }

  // row sums: reduce over the 4 k-chunk groups sharing a row
  sar += __shfl_xor(sar, 16);
  sar += __shfl_xor(sar, 32);
  const float inv = 1.0f / sar;    // lane l holds row l&15's scale

  // epilogue: C layout col=lr (+16cg), row=4g+reg
  #pragma unroll
  for (int reg = 0; reg < 4; ++reg) {
    const float invr = __shfl(inv, 4 * g + reg);
    const size_t ob = ((size_t)(b * 4096 + row0 + 4 * g + reg)) * 64 + lr;
    #pragma unroll
    for (int cg = 0; cg < 4; ++cg)
      out[ob + 16 * cg] = acc[cg][reg] * invr;
  }
}

extern "C" void kernel_launch(void* const* d_in, const int* in_sizes, int n_in,
                              void* d_out, int out_size, void* d_ws, size_t ws_size,
                              hipStream_t stream) {
  const float* h   = (const float*)d_in[0];
  const float* adj = (const float*)d_in[1];
  const float* W   = (const float*)d_in[2];
  const float* a   = (const float*)d_in[3];
  float* out = (float*)d_out;

  // ws layout: wt (2MB bf16, fragment order) | s1 (64KB) | s2 (64KB)
  unsigned short* wt = (unsigned short*)d_ws;
  float* s1 = (float*)(wt + (size_t)4 * 64 * 4096);
  float* s2 = s1 + 16384;

  k_wh  <<<512, 256, 0, stream>>>(h, W, a, wt, s1, s2);
  k_main<<<256, 256, 0, stream>>>(adj, wt, s1, s2, out);
}

// Round 13
// 66.519 us; speedup vs baseline: 1.2294x; 1.2294x over previous
//
#include <hip/hip_runtime.h>
#include <hip/hip_bf16.h>

// GAT layer, B=4, N=4096, F_in=128, F_out=64.
// out_i = sum_j adj_ij * exp(leaky(s2_i+s1_j)) * Wh_j / sum_j adj_ij*exp(..)
// (softmax normalizer cancels; eps*Z ~2e-9 relative -> dropped; scores O(8)
//  so bare exp2 safe; s1/s2 pre-scaled by log2 e.)
//
// R13: decide convoy-vs-DRAM-ceiling. R9 skeleton, K-split x2 (1024 blocks,
// each K=2048), K-step 128, per-thread ~108 VGPR (audited) -> (256,4) gives
// 4 blocks/CU = 4 barrier-groups with NO extra B traffic. Partials + combine.

typedef __attribute__((ext_vector_type(8))) short bf16x8;
typedef __attribute__((ext_vector_type(4))) float f32x4;
typedef __attribute__((ext_vector_type(4))) unsigned int u32x4;

#define LOG2E 1.4426950408889634f

__device__ __forceinline__ unsigned int pk2(float lo, float hi) {
  float2 f2; f2.x = lo; f2.y = hi;
  union { __hip_bfloat162 b; unsigned int u; } c;
  c.b = __float22bfloat162_rn(f2);
  return c.u;
}
__device__ __forceinline__ bf16x8 u2b(u32x4 v) {
  union { u32x4 u; bf16x8 b; } c; c.u = v; return c.b;
}
__device__ __forceinline__ float vexp2_(float x) {
  float r; asm("v_exp_f32 %0, %1" : "=v"(r) : "v"(x)); return r;
}

// ---------------- K1: Wh = h @ W (f32); wt bf16 in fragment order
//   segment S = (b*128 + k/32)*4 + col/16 (1KB); lane ((k%32)/8)*16+col%16
//   holds 8 shorts (k%8). s1 = Wh a1 * log2e, s2 = Wh a2 * log2e.
__global__ __launch_bounds__(256) void k_wh(
    const float* __restrict__ h, const float* __restrict__ W, const float* __restrict__ a,
    unsigned short* __restrict__ wt, float* __restrict__ s1, float* __restrict__ s2) {
  __shared__ float hs[32][130];
  __shared__ float Ws[128 * 64];
  const int t = threadIdx.x;
  const int b = blockIdx.x >> 7;
  const int row0 = (blockIdx.x & 127) << 5;

  #pragma unroll
  for (int it = 0; it < 8; ++it) {
    const int fidx = it * 256 + t;
    ((float4*)Ws)[fidx] = ((const float4*)W)[fidx];
  }
  #pragma unroll
  for (int it = 0; it < 4; ++it) {
    int flat = it * 256 + t;
    int r = flat >> 5, q = flat & 31;
    const float4 v = *(const float4*)(h + ((size_t)(b * 4096 + row0 + r)) * 128 + 4 * q);
    hs[r][4*q+0] = v.x; hs[r][4*q+1] = v.y; hs[r][4*q+2] = v.z; hs[r][4*q+3] = v.w;
  }
  __syncthreads();

  const int rg = t >> 4, cg = t & 15;
  float acc[2][4] = {};
  for (int k = 0; k < 128; ++k) {
    float4 wv = ((const float4*)Ws)[k * 16 + cg];
    #pragma unroll
    for (int i = 0; i < 2; ++i) {
      float hv = hs[2*rg + i][k];
      acc[i][0] = fmaf(hv, wv.x, acc[i][0]);
      acc[i][1] = fmaf(hv, wv.y, acc[i][1]);
      acc[i][2] = fmaf(hv, wv.z, acc[i][2]);
      acc[i][3] = fmaf(hv, wv.w, acc[i][3]);
    }
  }
  __syncthreads();

  float (*WhF)[68] = (float(*)[68])hs;
  #pragma unroll
  for (int i = 0; i < 2; ++i)
    #pragma unroll
    for (int j = 0; j < 4; ++j)
      WhF[2*rg + i][4*cg + j] = acc[i][j];
  __syncthreads();

  if (t < 32) {
    float x1 = 0.f, x2 = 0.f;
    #pragma unroll 8
    for (int c = 0; c < 64; ++c) {
      float v = WhF[t][c];
      x1 = fmaf(v, a[c], x1);
      x2 = fmaf(v, a[64 + c], x2);
    }
    s1[b * 4096 + row0 + t] = x1 * LOG2E;
    s2[b * 4096 + row0 + t] = x2 * LOG2E;
  }

  const int col = t >> 2, sub = t & 3;
  unsigned int uh[4];
  #pragma unroll
  for (int r = 0; r < 4; ++r)
    uh[r] = pk2(WhF[8*sub + 2*r][col], WhF[8*sub + 2*r + 1][col]);
  const int S = (b * 128 + (row0 >> 5)) * 4 + (col >> 4);
  unsigned short* dst = wt + ((size_t)S << 9) + sub * 128 + (col & 15) * 8;
  *(uint4*)dst = make_uint4(uh[0], uh[1], uh[2], uh[3]);
}

// ---------------- K3: partial = P @ Wh over half the K range.
// 1024 blocks x 256 thr, 4 blocks/CU. Block: 32-row tile, K half (2048),
// K-step 128 (16 steps). Wave w: P rows 8w..8w+7 (lane: rows 8w+4*(l>>5)+r,
// cols 4*(l&31)..+4), MFMA cols 16w..16w+16 (fragment-order B, bv[4]).
__global__ __launch_bounds__(256, 4) void k_main(
    const float* __restrict__ adj, const unsigned short* __restrict__ wt,
    const float* __restrict__ s1, const float* __restrict__ s2,
    float* __restrict__ part) {
  __shared__ unsigned short Pws[2][4096];   // [buf][32 rows][128 shorts] swizzled
  __shared__ float Ss[32];

  const int t = threadIdx.x;
  const int blk = blockIdx.x;
  const int xcd = blk & 7;                    // default round-robin XCD id
  const int b = xcd >> 1;                     // one batch per XCD pair
  const int u = (blk >> 3) | ((xcd & 1) << 7);   // 0..255 per b, bijective
  const int tile = u & 127, half = u >> 7;
  const int row0 = tile << 5;
  const int k0 = half << 11;                  // K offset (2048)
  const int l = t & 63, w = t >> 6;
  const int lr = l & 15, g = l >> 4;
  const int lh = l >> 5, lc = l & 31;

  const float* adjW = adj + ((size_t)(b * 4096 + row0 + 8 * w + 4 * lh)) * 4096 + k0 + 4 * lc;
  const float* s1W  = s1 + b * 4096 + k0 + 4 * lc;
  // fragment-order B base: segment (b*128 + half*64 + k32loc)*4 + w
  const unsigned short* wtW = wt + (((size_t)(b * 512 + half * 256 + w)) << 9) + 8 * l;

  float s2r[4];
  #pragma unroll
  for (int r = 0; r < 4; ++r)
    s2r[r] = s2[b * 4096 + row0 + 8 * w + 4 * lh + r];

  float sar[4] = {0.f, 0.f, 0.f, 0.f};
  f32x4 acc0 = {0.f, 0.f, 0.f, 0.f}, acc1 = {0.f, 0.f, 0.f, 0.f};

  f32x4 aX[4], aY[4], sX, sY;
  u32x4 bv[4];

#define LOADADJ(av, sv, ks) do {                                              \
    const int ko = ((ks) & 15) << 7;                                          \
    _Pragma("unroll")                                                         \
    for (int r = 0; r < 4; ++r)                                               \
      av[r] = *(const f32x4*)(adjW + (size_t)r * 4096 + ko);                  \
    sv = *(const f32x4*)(s1W + ko);                                           \
  } while (0)

  // 4 contiguous 1KB fragment loads; consecutive k32 = 4 segments = 2048 shorts
#define LOADB(ks) do {                                                        \
    const int ksm = (ks) & 15;                                                \
    _Pragma("unroll")                                                         \
    for (int kk = 0; kk < 4; ++kk)                                            \
      bv[kk] = *(const u32x4*)(wtW + ((size_t)(ksm * 4 + kk) << 11));         \
  } while (0)

  // lane: rows 8w+4lh+r (r=0..3), cols [4lc,4lc+4). Swizzled P write:
  // col c of row rl lives at short-offset c ^ ((rl&7)<<3)  (j<4 safe: bits 0-1)
#define PBUILD(av, sv, buf) do {                                              \
    unsigned short* Pd = &Pws[buf][0];                                        \
    _Pragma("unroll")                                                         \
    for (int r = 0; r < 4; ++r) {                                             \
      const int rl = 8 * w + 4 * lh + r;                                      \
      float e0 = s2r[r] + sv[0], e1 = s2r[r] + sv[1];                         \
      float e2 = s2r[r] + sv[2], e3 = s2r[r] + sv[3];                         \
      e0 = fmaxf(e0, 0.2f * e0); e1 = fmaxf(e1, 0.2f * e1);                   \
      e2 = fmaxf(e2, 0.2f * e2); e3 = fmaxf(e3, 0.2f * e3);                   \
      float p0 = vexp2_(e0), p1 = vexp2_(e1);                                 \
      float p2 = vexp2_(e2), p3 = vexp2_(e3);                                 \
      float w0 = av[r][0] * p0, w1 = av[r][1] * p1;                           \
      float w2 = av[r][2] * p2, w3 = av[r][3] * p3;                           \
      sar[r] += (w0 + w1) + (w2 + w3);                                        \
      uint2 pk; pk.x = pk2(w0, w1); pk.y = pk2(w2, w3);                       \
      *(uint2*)(Pd + rl * 128 + ((4 * lc) ^ ((rl & 7) << 3))) = pk;           \
    }                                                                         \
  } while (0)

#define SYNC() do {                                                           \
    asm volatile("s_waitcnt lgkmcnt(0)" ::: "memory");                        \
    __builtin_amdgcn_sched_barrier(0);                                        \
    __builtin_amdgcn_s_barrier();                                             \
    __builtin_amdgcn_sched_barrier(0);                                        \
  } while (0)

#define MFMAP(buf) do {                                                       \
    const unsigned short* Pr = &Pws[buf][0];                                  \
    _Pragma("unroll")                                                         \
    for (int kk = 0; kk < 4; ++kk) {                                          \
      const int koff = (8 * g + 32 * kk) ^ ((lr & 7) << 3);                   \
      bf16x8 a0 = *(const bf16x8*)(Pr + lr * 128 + koff);                     \
      bf16x8 a1 = *(const bf16x8*)(Pr + (16 + lr) * 128 + koff);              \
      acc0 = __builtin_amdgcn_mfma_f32_16x16x32_bf16(a0, u2b(bv[kk]), acc0, 0, 0, 0); \
      acc1 = __builtin_amdgcn_mfma_f32_16x16x32_bf16(a1, u2b(bv[kk]), acc1, 0, 0, 0); \
    }                                                                         \
  } while (0)

  LOADADJ(aX, sX, 0);
  LOADADJ(aY, sY, 1);
  LOADB(0);

  for (int it = 0; it < 8; ++it) {
    PBUILD(aX, sX, 0);
    LOADADJ(aX, sX, 2 * it + 2);   // depth-2 HBM prefetch (wraps harmlessly)
    SYNC();                        // lgkm only: HBM prefetch stays in flight
    MFMAP(0);
    LOADB(2 * it + 1);             // L2 B for next step

    PBUILD(aY, sY, 1);
    LOADADJ(aY, sY, 2 * it + 3);
    SYNC();
    MFMAP(1);
    LOADB(2 * it + 2);
  }

  // S row sums: butterfly within each 32-lane half (rows disjoint per half)
  #pragma unroll
  for (int r = 0; r < 4; ++r) {
    float v = sar[r];
    #pragma unroll
    for (int m = 1; m < 32; m <<= 1) v += __shfl_xor(v, m);
    if (lc == 0) Ss[8 * w + 4 * lh + r] = v;
  }
  __syncthreads();

  // write partial: [2048] num (32x64 row-major) | [32] S
  float* pb = part + ((size_t)((b * 128 + tile) * 2 + half)) * 2080;
  #pragma unroll
  for (int reg = 0; reg < 4; ++reg) {
    const int r0 = 4 * g + reg, r1 = 16 + 4 * g + reg;
    pb[r0 * 64 + 16 * w + lr] = acc0[reg];
    pb[r1 * 64 + 16 * w + lr] = acc1[reg];
  }
  if (t < 32) pb[2048 + t] = Ss[t];
}

// ---------------- K4: combine 2 half-K partials, scale, write out
__global__ __launch_bounds__(256) void k_final(
    const float* __restrict__ part, float* __restrict__ out) {
  const int t = threadIdx.x;
  const int tt = blockIdx.x;               // 0..511 = b*128 + tile
  const float* pb = part + (size_t)tt * 4160;
  __shared__ float invs[32];
  if (t < 32) invs[t] = 1.0f / (pb[2048 + t] + pb[2080 + 2048 + t]);
  __syncthreads();
  #pragma unroll
  for (int e = 0; e < 8; ++e) {
    const int idx = e * 256 + t;
    const int r = idx >> 6, c = idx & 63;
    const float v = pb[idx] + pb[2080 + idx];
    out[((size_t)(tt * 32 + r)) * 64 + c] = v * invs[r];
  }
}

extern "C" void kernel_launch(void* const* d_in, const int* in_sizes, int n_in,
                              void* d_out, int out_size, void* d_ws, size_t ws_size,
                              hipStream_t stream) {
  const float* h   = (const float*)d_in[0];
  const float* adj = (const float*)d_in[1];
  const float* W   = (const float*)d_in[2];
  const float* a   = (const float*)d_in[3];
  float* out = (float*)d_out;

  // ws: wt (2MB) | s1 (64KB) | s2 (64KB) | partials (512*2*2080*4B = 8.5MB)
  unsigned short* wt = (unsigned short*)d_ws;
  float* s1 = (float*)(wt + (size_t)4 * 64 * 4096);
  float* s2 = s1 + 16384;
  float* part = s2 + 16384;

  k_wh   <<<512, 256, 0, stream>>>(h, W, a, wt, s1, s2);
  k_main <<<1024, 256, 0, stream>>>(adj, wt, s1, s2, part);
  k_final<<<512, 256, 0, stream>>>(part, out);
}